// Round 1
// baseline (725.269 us; speedup 1.0000x reference)
//
#include <hip/hip_runtime.h>

// Chunked VMM with per-128-K-chunk ADC quantization.
//   out[b,n] = sum_{c} q( sum_{k in chunk c} x[b,k]*w[n,k] ) + bias[n]
//   q(p) = round(clip(p,+-2.56) * 255/2.56) * 2.56/255   (round = RTNE)
// Strategy: cast x -> bf16, cast w -> bf16 PRE-SCALED by s=255/2.56 so GEMM
// partials are directly in ADC units; per chunk: med3 clamp, v_rndne, add to
// master accumulator. Final: out = master * (2.56/255) + bias.
// GEMM = m97-structure: 128x128 tile, BK=64, 4 waves x 64x64 (4x4 of
// mfma_f32_16x16x32_bf16), global_load_lds width=16.

typedef __attribute__((ext_vector_type(8))) short short8;    // 8 bf16 = 4 VGPRs
typedef __attribute__((ext_vector_type(4))) float floatx4;   // MFMA C/D

#define BM 128
#define BN 128
#define BK 64

static __device__ __forceinline__ unsigned short f2bf(float f) {
    union { float f; unsigned int u; } v; v.f = f;
    unsigned int u = v.u;
    unsigned int r = (u + 0x7fffu + ((u >> 16) & 1u)) >> 16;  // RTNE
    return (unsigned short)r;
}

__global__ void cast_x_kernel(const float* __restrict__ in,
                              unsigned short* __restrict__ out, int n4) {
    int i = blockIdx.x * 256 + threadIdx.x;
    if (i >= n4) return;
    float4 v = ((const float4*)in)[i];
    ushort4 o;
    o.x = f2bf(v.x); o.y = f2bf(v.y); o.z = f2bf(v.z); o.w = f2bf(v.w);
    ((ushort4*)out)[i] = o;
}

__global__ void cast_w_kernel(const float* __restrict__ in,
                              unsigned short* __restrict__ out, int n4) {
    const float s = 99.609375f;  // 255/2.56 exact
    int i = blockIdx.x * 256 + threadIdx.x;
    if (i >= n4) return;
    float4 v = ((const float4*)in)[i];
    ushort4 o;
    o.x = f2bf(v.x * s); o.y = f2bf(v.y * s); o.z = f2bf(v.z * s); o.w = f2bf(v.w * s);
    ((ushort4*)out)[i] = o;
}

__global__ __launch_bounds__(256, 2) void vmm_kernel(
    const unsigned short* __restrict__ A,   // x   [B,K] bf16
    const unsigned short* __restrict__ Bw,  // w*s [N,K] bf16 (K-contiguous: B^T gemm)
    const float* __restrict__ bias,
    float* __restrict__ out,
    int N, int K)
{
    __shared__ unsigned short sA[BM * BK];
    __shared__ unsigned short sB[BN * BK];

    const int tid  = threadIdx.x;
    const int wid  = tid >> 6;
    const int lane = tid & 63;

    const int m0 = blockIdx.y * BM;
    const int n0 = blockIdx.x * BN;

    const int waveM = (wid >> 1) * 64;
    const int waveN = (wid & 1) * 64;

    floatx4 acc[4][4];   // partial (ADC units), reset every 128 K
    floatx4 macc[4][4];  // master accumulator
    #pragma unroll
    for (int i = 0; i < 4; ++i)
        #pragma unroll
        for (int j = 0; j < 4; ++j) {
            acc[i][j]  = (floatx4){0.f, 0.f, 0.f, 0.f};
            macc[i][j] = (floatx4){0.f, 0.f, 0.f, 0.f};
        }

    // staging: 16 segments of 1 KiB (8 rows x 64 cols bf16); 8 lanes/row, 16B/lane
    const int srow = lane >> 3;          // row within segment
    const int scol = (lane & 7) * 8;     // bf16 col offset

    const unsigned short* gA = A  + (long)m0 * K;
    const unsigned short* gB = Bw + (long)n0 * K;

    for (int k0 = 0; k0 < K; k0 += BK) {
        #pragma unroll
        for (int i = 0; i < 4; ++i) {
            const int seg = i * 4 + wid;                 // wave-uniform
            const long grow = (long)(seg * 8 + srow);
            __builtin_amdgcn_global_load_lds(
                (const __attribute__((address_space(1))) void*)(gA + grow * K + k0 + scol),
                (__attribute__((address_space(3))) void*)(sA + seg * 512),
                16, 0, 0);
            __builtin_amdgcn_global_load_lds(
                (const __attribute__((address_space(1))) void*)(gB + grow * K + k0 + scol),
                (__attribute__((address_space(3))) void*)(sB + seg * 512),
                16, 0, 0);
        }
        __syncthreads();   // drains vmcnt -> LDS tiles ready

        #pragma unroll
        for (int kk = 0; kk < BK; kk += 32) {
            const int krd = kk + (lane >> 4) * 8;
            short8 af[4], bfr[4];
            #pragma unroll
            for (int tm = 0; tm < 4; ++tm)
                af[tm] = *(const short8*)(sA + (waveM + tm * 16 + (lane & 15)) * BK + krd);
            #pragma unroll
            for (int tn = 0; tn < 4; ++tn)
                bfr[tn] = *(const short8*)(sB + (waveN + tn * 16 + (lane & 15)) * BK + krd);
            #pragma unroll
            for (int tm = 0; tm < 4; ++tm)
                #pragma unroll
                for (int tn = 0; tn < 4; ++tn)
                    acc[tm][tn] = __builtin_amdgcn_mfma_f32_16x16x32_bf16(
                        af[tm], bfr[tn], acc[tm][tn], 0, 0, 0);
        }

        // ADC quantize at each 128-K chunk boundary (every 2nd BK iter)
        if (((k0 + BK) & 127) == 0) {
            #pragma unroll
            for (int tm = 0; tm < 4; ++tm)
                #pragma unroll
                for (int tn = 0; tn < 4; ++tn) {
                    #pragma unroll
                    for (int r = 0; r < 4; ++r) {
                        float v = acc[tm][tn][r];
                        v = __builtin_amdgcn_fmed3f(v, -255.0f, 255.0f); // clamp
                        v = __builtin_rintf(v);                          // v_rndne
                        macc[tm][tn][r] += v;
                    }
                    acc[tm][tn] = (floatx4){0.f, 0.f, 0.f, 0.f};
                }
        }
        __syncthreads();   // protect LDS before next stage
    }

    const float invs = 2.56f / 255.0f;
    #pragma unroll
    for (int tn = 0; tn < 4; ++tn) {
        const int col = n0 + waveN + tn * 16 + (lane & 15);
        const float bv = bias[col];
        #pragma unroll
        for (int tm = 0; tm < 4; ++tm) {
            const int row = m0 + waveM + tm * 16 + (lane >> 4) * 4;
            #pragma unroll
            for (int r = 0; r < 4; ++r)
                out[(long)(row + r) * N + col] = macc[tm][tn][r] * invs + bv;
        }
    }
}

extern "C" void kernel_launch(void* const* d_in, const int* in_sizes, int n_in,
                              void* d_out, int out_size, void* d_ws, size_t ws_size,
                              hipStream_t stream) {
    const float* x    = (const float*)d_in[0];
    const float* w    = (const float*)d_in[1];
    const float* bias = (const float*)d_in[2];
    // d_in[3] = layer (unused)

    const int N = in_sizes[2];
    const int K = in_sizes[1] / N;
    const int B = in_sizes[0] / K;
    float* out = (float*)d_out;

    // workspace layout: bf16 x [B*K], bf16 w*s [N*K]  (needs ~101 MB)
    unsigned short* xb = (unsigned short*)d_ws;
    unsigned short* wb = xb + (size_t)B * K;

    {
        int n4 = (int)(((long)B * K) / 4);
        cast_x_kernel<<<(n4 + 255) / 256, 256, 0, stream>>>(x, xb, n4);
    }
    {
        int n4 = (int)(((long)N * K) / 4);
        cast_w_kernel<<<(n4 + 255) / 256, 256, 0, stream>>>(w, wb, n4);
    }
    dim3 grid(N / BN, B / BM);
    vmm_kernel<<<grid, 256, 0, stream>>>(xb, wb, bias, out, N, K);
}